// Round 3
// baseline (321.833 us; speedup 1.0000x reference)
//
#include <hip/hip_runtime.h>
#include <hip/hip_bf16.h>

// Problem constants (B=4, T=4096, D=1024). FP32 I/O, bf16 MFMA internally.
#define BB 4
#define TT 4096
#define DD 1024
#define MM (BB * TT)   // 16384 rows
#define LN_EPS 1e-5f

#define NC 64
#define CL 64   // chunk length

typedef __attribute__((ext_vector_type(8))) short bf16x8;    // 8 bf16 = 4 VGPRs
typedef __attribute__((ext_vector_type(4))) float f32x4;
typedef __attribute__((ext_vector_type(16))) float f32x16;   // 32x32 acc

__device__ __forceinline__ float bfbits2f(unsigned short h) {
    return __uint_as_float(((unsigned int)h) << 16);
}
__device__ __forceinline__ unsigned short f2bfbits(float f) {
    __hip_bfloat16 h = __float2bfloat16(f);
    return *reinterpret_cast<unsigned short*>(&h);
}
__device__ __forceinline__ unsigned int pack2(float a, float b) {
    return (unsigned int)f2bfbits(a) | ((unsigned int)f2bfbits(b) << 16);
}

// async global->LDS, 16B per lane (wave-uniform LDS base + lane*16).
__device__ __forceinline__ void async_copy16(void* lds, const void* g) {
    __builtin_amdgcn_global_load_lds(
        (const __attribute__((address_space(1))) void*)g,
        (__attribute__((address_space(3))) void*)lds,
        16, 0, 0);
}

// ---------------------------------------------------------------------------
// fp32 -> bf16 conversion of the 3 weight matrices in ONE launch.
// ---------------------------------------------------------------------------
__global__ __launch_bounds__(256)
void convert_w3(const float* __restrict__ s0, const float* __restrict__ s1,
                const float* __restrict__ s2,
                __hip_bfloat16* __restrict__ d0, __hip_bfloat16* __restrict__ d1,
                __hip_bfloat16* __restrict__ d2)
{
    const int blk = blockIdx.x;
    const int w = blk >> 10;
    const float* src = (w == 0) ? s0 : (w == 1) ? s1 : s2;
    __hip_bfloat16* dst = (w == 0) ? d0 : (w == 1) ? d1 : d2;
    const size_t i = ((size_t)(blk & 1023) * 256 + threadIdx.x) * 4;
    float4 v = *(const float4*)(src + i);
    uint2 o;
    o.x = pack2(v.x, v.y);
    o.y = pack2(v.z, v.w);
    *(uint2*)((unsigned short*)dst + i) = o;
}

// ---------------------------------------------------------------------------
// LayerNorm: fp32 in -> bf16 out. One WAVE per row (4 rows / 256-thr block).
// ---------------------------------------------------------------------------
__global__ __launch_bounds__(256)
void ln_kernel(const float* __restrict__ x,
               const float* __restrict__ w,
               const float* __restrict__ b,
               __hip_bfloat16* __restrict__ out)
{
    const int wv   = threadIdx.x >> 6;
    const int lane = threadIdx.x & 63;
    const int row  = blockIdx.x * 4 + wv;

    const float* xr = x + (size_t)row * DD + lane * 16;
    float4 v[4];
    #pragma unroll
    for (int i = 0; i < 4; ++i) v[i] = *(const float4*)(xr + i * 4);

    float s = 0.0f, ss = 0.0f;
    #pragma unroll
    for (int i = 0; i < 4; ++i) {
        s  += (v[i].x + v[i].y) + (v[i].z + v[i].w);
        ss += fmaf(v[i].x, v[i].x, fmaf(v[i].y, v[i].y,
              fmaf(v[i].z, v[i].z, v[i].w * v[i].w)));
    }
    #pragma unroll
    for (int o = 32; o > 0; o >>= 1) {
        s  += __shfl_down(s, o);
        ss += __shfl_down(ss, o);
    }
    s  = __shfl(s, 0);
    ss = __shfl(ss, 0);

    const float mu   = s * (1.0f / DD);
    const float var  = ss * (1.0f / DD) - mu * mu;
    const float rstd = rsqrtf(var + LN_EPS);

    unsigned int res[8];
    #pragma unroll
    for (int i = 0; i < 4; ++i) {
        float4 wr = *(const float4*)(w + lane * 16 + i * 4);
        float4 br = *(const float4*)(b + lane * 16 + i * 4);
        float o0 = (v[i].x - mu) * rstd * wr.x + br.x;
        float o1 = (v[i].y - mu) * rstd * wr.y + br.y;
        float o2 = (v[i].z - mu) * rstd * wr.z + br.z;
        float o3 = (v[i].w - mu) * rstd * wr.w + br.w;
        res[i * 2]     = pack2(o0, o1);
        res[i * 2 + 1] = pack2(o2, o3);
    }
    unsigned short* op = (unsigned short*)out + (size_t)row * DD + lane * 16;
    *(uint4*)op       = make_uint4(res[0], res[1], res[2], res[3]);
    *(uint4*)(op + 8) = make_uint4(res[4], res[5], res[6], res[7]);
}

// ---------------------------------------------------------------------------
// Fused dual GEMM + gate + CHUNK-SUM epilogue. Round-0 2-barrier structure
// (single-buffer LDS, ~3 blocks/CU, proven 81 us) with 32x32x16 MFMA:
//   - same bytes staged / ds_read count; MFMA inst count halves (64->32/tile)
//   - 32x32 pipe: ~8.07 cyc / 32768 FLOP vs 2x4.85 / 2x16384 (-20% pipe time)
//   - C/D map (m74/m101, swapped operands): m = lane&31,
//     n = (reg&3) + 8*(reg>>2) + 4*(lane>>5)
//   - input frags: lane -> row lane&31, k-chunk lane>>5 (8 bf16)
//   - XOR swizzle unchanged; per 16-lane quarter: 8 slots x 2 rows = free.
// ---------------------------------------------------------------------------
__global__ __launch_bounds__(256, 2)
void dual_gemm_gate(const __hip_bfloat16* __restrict__ A,
                    const __hip_bfloat16* __restrict__ Wg,
                    const __hip_bfloat16* __restrict__ Wv,
                    const float* __restrict__ gb,
                    const float* __restrict__ vb,
                    __hip_bfloat16* __restrict__ U,
                    float* __restrict__ Pk,
                    int M, int N, int K)
{
    constexpr int BK = 64;
    __shared__ short As[128 * BK];   // 16 KB each
    __shared__ short Bg[128 * BK];
    __shared__ short Bv[128 * BK];

    const int tid  = threadIdx.x;
    const int m0   = blockIdx.x * 128;
    const int n0   = blockIdx.y * 128;
    const int wave = tid >> 6;
    const int lane = tid & 63;
    const int wm   = (wave & 1) * 64;
    const int wn   = (wave >> 1) * 64;
    const int l31  = lane & 31;      // fragment row
    const int hi   = lane >> 5;      // k-chunk half
    const int swz  = lane & 7;       // read-side swizzle key (= row&7)

    f32x16 accg[2][2] = {};
    f32x16 accv[2][2] = {};

    // staging: slot = r*256+tid -> row = slot>>3 (0..127), chunk = slot&7.
    // lane fetches global chunk (slot&7) ^ (row&7)  [XOR self-inverse]
    const __hip_bfloat16* gA[4];
    const __hip_bfloat16* gG[4];
    const __hip_bfloat16* gV[4];
    #pragma unroll
    for (int r = 0; r < 4; ++r) {
        const int slot = r * 256 + tid;
        const int srow = slot >> 3;
        const int gcc  = (slot & 7) ^ (srow & 7);
        gA[r] = A  + (size_t)(m0 + srow) * K + gcc * 8;
        gG[r] = Wg + (size_t)(n0 + srow) * K + gcc * 8;
        gV[r] = Wv + (size_t)(n0 + srow) * K + gcc * 8;
    }

    for (int k0 = 0; k0 < K; k0 += BK) {
        #pragma unroll
        for (int r = 0; r < 4; ++r) {
            async_copy16(&As[(r * 256 + tid) * 8], gA[r] + k0);
            async_copy16(&Bg[(r * 256 + tid) * 8], gG[r] + k0);
            async_copy16(&Bv[(r * 256 + tid) * 8], gV[r] + k0);
        }
        __builtin_amdgcn_s_waitcnt(0);
        __syncthreads();

        #pragma unroll
        for (int kk = 0; kk < 4; ++kk) {          // 4 k-steps of 16
            const int co = ((kk * 2 + hi) ^ swz) * 8;   // swizzled 16B chunk
            bf16x8 af[2], bgf[2], bvf[2];
            #pragma unroll
            for (int i = 0; i < 2; ++i)
                af[i] = *(const bf16x8*)&As[(wm + i * 32 + l31) * BK + co];
            #pragma unroll
            for (int j = 0; j < 2; ++j) {
                bgf[j] = *(const bf16x8*)&Bg[(wn + j * 32 + l31) * BK + co];
                bvf[j] = *(const bf16x8*)&Bv[(wn + j * 32 + l31) * BK + co];
            }
            #pragma unroll
            for (int i = 0; i < 2; ++i)
                #pragma unroll
                for (int j = 0; j < 2; ++j) {
                    accg[i][j] = __builtin_amdgcn_mfma_f32_32x32x16_bf16(
                        bgf[j], af[i], accg[i][j], 0, 0, 0);
                    accv[i][j] = __builtin_amdgcn_mfma_f32_32x32x16_bf16(
                        bvf[j], af[i], accv[i][j], 0, 0, 0);
                }
        }
        __syncthreads();
    }

    // chunk id for this wave's 64 m-rows (m0+wm .. m0+wm+63 = one chunk)
    const int chrow = m0 + wm;
    const int cb    = chrow >> 12;             // / TT
    const int cc    = (chrow & (TT - 1)) >> 6; // chunk within batch

    #pragma unroll
    for (int j = 0; j < 2; ++j) {
        #pragma unroll
        for (int q = 0; q < 4; ++q) {          // reg-quad: n = nb + 0..3
            const int nb = n0 + wn + j * 32 + hi * 4 + q * 8;
            const float4 gb4 = *(const float4*)(gb + nb);
            const float4 vb4 = *(const float4*)(vb + nb);
            float4 ps = make_float4(0.f, 0.f, 0.f, 0.f);
            #pragma unroll
            for (int i = 0; i < 2; ++i) {
                const int m = m0 + wm + i * 32 + l31;
                const float g0 = accg[i][j][q*4+0] + gb4.x, v0 = accv[i][j][q*4+0] + vb4.x;
                const float g1 = accg[i][j][q*4+1] + gb4.y, v1 = accv[i][j][q*4+1] + vb4.y;
                const float g2 = accg[i][j][q*4+2] + gb4.z, v2 = accv[i][j][q*4+2] + vb4.z;
                const float g3 = accg[i][j][q*4+3] + gb4.w, v3 = accv[i][j][q*4+3] + vb4.w;
                const float u0 = (2.0f / (1.0f + __expf(-g0)) - 1.0f) * v0;
                const float u1 = (2.0f / (1.0f + __expf(-g1)) - 1.0f) * v1;
                const float u2 = (2.0f / (1.0f + __expf(-g2)) - 1.0f) * v2;
                const float u3 = (2.0f / (1.0f + __expf(-g3)) - 1.0f) * v3;
                ps.x += u0; ps.y += u1; ps.z += u2; ps.w += u3;
                uint2 o;
                o.x = pack2(u0, u1);
                o.y = pack2(u2, u3);
                *(uint2*)((unsigned short*)U + (size_t)m * N + nb) = o;
            }
            // reduce across the 32 l31-lanes (all m-rows of the chunk)
            #pragma unroll
            for (int mk = 1; mk <= 16; mk <<= 1) {
                ps.x += __shfl_xor(ps.x, mk);
                ps.y += __shfl_xor(ps.y, mk);
                ps.z += __shfl_xor(ps.z, mk);
                ps.w += __shfl_xor(ps.w, mk);
            }
            if (l31 == 0)
                *(float4*)&Pk[((size_t)cb * NC + cc) * DD + nb] = ps;
        }
    }
}

// ---------------------------------------------------------------------------
// Final GEMM: out[m,n] = X[m,n] + sum_k S[m,k]*Wo[n,k] + ob[n]
// Round-0 2-barrier structure, 32x32x16 MFMA, float4 loads/stores.
// ---------------------------------------------------------------------------
__global__ __launch_bounds__(256, 2)
void gemm_out(const __hip_bfloat16* __restrict__ A,
              const __hip_bfloat16* __restrict__ W,
              const float* __restrict__ bias,
              const float* __restrict__ X,
              float* __restrict__ C,
              int M, int N, int K)
{
    constexpr int BK = 64;
    __shared__ short As[128 * BK];
    __shared__ short Bs[128 * BK];

    const int tid  = threadIdx.x;
    const int m0   = blockIdx.x * 128;
    const int n0   = blockIdx.y * 128;
    const int wave = tid >> 6;
    const int lane = tid & 63;
    const int wm   = (wave & 1) * 64;
    const int wn   = (wave >> 1) * 64;
    const int l31  = lane & 31;
    const int hi   = lane >> 5;
    const int swz  = lane & 7;

    f32x16 acc[2][2] = {};

    const __hip_bfloat16* gA[4];
    const __hip_bfloat16* gB[4];
    #pragma unroll
    for (int r = 0; r < 4; ++r) {
        const int slot = r * 256 + tid;
        const int srow = slot >> 3;
        const int gcc  = (slot & 7) ^ (srow & 7);
        gA[r] = A + (size_t)(m0 + srow) * K + gcc * 8;
        gB[r] = W + (size_t)(n0 + srow) * K + gcc * 8;
    }

    for (int k0 = 0; k0 < K; k0 += BK) {
        #pragma unroll
        for (int r = 0; r < 4; ++r) {
            async_copy16(&As[(r * 256 + tid) * 8], gA[r] + k0);
            async_copy16(&Bs[(r * 256 + tid) * 8], gB[r] + k0);
        }
        __builtin_amdgcn_s_waitcnt(0);
        __syncthreads();

        #pragma unroll
        for (int kk = 0; kk < 4; ++kk) {
            const int co = ((kk * 2 + hi) ^ swz) * 8;
            bf16x8 af[2], bfr[2];
            #pragma unroll
            for (int i = 0; i < 2; ++i)
                af[i] = *(const bf16x8*)&As[(wm + i * 32 + l31) * BK + co];
            #pragma unroll
            for (int j = 0; j < 2; ++j)
                bfr[j] = *(const bf16x8*)&Bs[(wn + j * 32 + l31) * BK + co];
            #pragma unroll
            for (int i = 0; i < 2; ++i)
                #pragma unroll
                for (int j = 0; j < 2; ++j)
                    acc[i][j] = __builtin_amdgcn_mfma_f32_32x32x16_bf16(
                        bfr[j], af[i], acc[i][j], 0, 0, 0);
        }
        __syncthreads();
    }

    #pragma unroll
    for (int j = 0; j < 2; ++j) {
        #pragma unroll
        for (int q = 0; q < 4; ++q) {
            const int nb = n0 + wn + j * 32 + hi * 4 + q * 8;
            const float4 bv = *(const float4*)(bias + nb);
            #pragma unroll
            for (int i = 0; i < 2; ++i) {
                const int m = m0 + wm + i * 32 + l31;
                const size_t idx = (size_t)m * N + nb;
                const float4 xv = *(const float4*)(X + idx);
                float4 o;
                o.x = acc[i][j][q*4+0] + bv.x + xv.x;
                o.y = acc[i][j][q*4+1] + bv.y + xv.y;
                o.z = acc[i][j][q*4+2] + bv.z + xv.z;
                o.w = acc[i][j][q*4+3] + bv.w + xv.w;
                *(float4*)(C + idx) = o;
            }
        }
    }
}

// ---------------------------------------------------------------------------
// Exclusive prefix over chunks, LDS-tile version. 64 blocks x 256 thr.
// ---------------------------------------------------------------------------
__global__ __launch_bounds__(256)
void scan_offsets(float* __restrict__ Pk)
{
    __shared__ float Tl[64][68];   // [chunk][col], pad 68 (272B rows)
    __shared__ float Seg[4][64];

    const int tid  = threadIdx.x;
    const int col0 = blockIdx.x * 64;
    const int b    = col0 >> 10;
    const int d0   = col0 & 1023;

    #pragma unroll
    for (int r = 0; r < 4; ++r) {
        const int idx = r * 256 + tid;
        const int c = idx >> 4, q = idx & 15;
        float4 v = *(const float4*)&Pk[((size_t)b * NC + c) * DD + d0 + q * 4];
        *(float4*)&Tl[c][q * 4] = v;
    }
    __syncthreads();

    const int j = tid & 63, seg = tid >> 6;
    float ssum = 0.0f;
    #pragma unroll
    for (int k = 0; k < 16; ++k) ssum += Tl[seg * 16 + k][j];
    Seg[seg][j] = ssum;
    __syncthreads();

    float run = 0.0f;
    for (int s = 0; s < seg; ++s) run += Seg[s][j];
    #pragma unroll
    for (int k = 0; k < 16; ++k) {
        const int c = seg * 16 + k;
        const float v = Tl[c][j];
        Tl[c][j] = run;
        run += v;
    }
    __syncthreads();

    #pragma unroll
    for (int r = 0; r < 4; ++r) {
        const int idx = r * 256 + tid;
        const int c = idx >> 4, q = idx & 15;
        *(float4*)&Pk[((size_t)b * NC + c) * DD + d0 + q * 4] =
            *(const float4*)&Tl[c][q * 4];
    }
}

// ---------------------------------------------------------------------------
// Within-chunk inclusive scan + decay -> S (bf16). grid (NC, BB) x 128 thr.
// ---------------------------------------------------------------------------
__global__ __launch_bounds__(128)
void scan_final(const __hip_bfloat16* __restrict__ U,
                const float* __restrict__ Pk,
                const float* __restrict__ log_decay,
                __hip_bfloat16* __restrict__ S)
{
    const int c = blockIdx.x, b = blockIdx.y;
    const int d8 = threadIdx.x * 8;

    const float ld = log_decay[0];
    const float alpha = log1pf(__expf(ld));          // softplus
    const float ratio = __expf(-alpha);
    float dec = __expf(-alpha * (float)(c * CL));

    const float* pk = &Pk[((size_t)b * NC + c) * DD + d8];
    float run[8];
    float4 r0 = *(const float4*)pk;
    float4 r1 = *(const float4*)(pk + 4);
    run[0] = r0.x; run[1] = r0.y; run[2] = r0.z; run[3] = r0.w;
    run[4] = r1.x; run[5] = r1.y; run[6] = r1.z; run[7] = r1.w;

    const size_t base = ((size_t)b * TT + (size_t)c * CL) * DD + d8;
    const unsigned short* up = (const unsigned short*)U + base;
    unsigned short* sp = (unsigned short*)S + base;

    #pragma unroll 8
    for (int t = 0; t < CL; ++t) {
        uint4 raw = *(const uint4*)(up + (size_t)t * DD);
        unsigned int wds[4] = {raw.x, raw.y, raw.z, raw.w};
        uint4 o;
        unsigned int* ow = (unsigned int*)&o;
        #pragma unroll
        for (int k = 0; k < 4; ++k) {
            run[2 * k]     += bfbits2f((unsigned short)(wds[k] & 0xFFFF));
            run[2 * k + 1] += bfbits2f((unsigned short)(wds[k] >> 16));
            ow[k] = pack2(run[2 * k] * dec, run[2 * k + 1] * dec);
        }
        *(uint4*)(sp + (size_t)t * DD) = o;
        dec *= ratio;
    }
}

// ---------------------------------------------------------------------------
// Workspace: 39 MB. normed/S 32 MB | Pk 1 MB | Wg/Wv/Wo bf16 2 MB each.
// U (bf16, 32 MB) lives in d_out (fp32 64 MB); dead before gemm_out writes.
// ---------------------------------------------------------------------------
extern "C" void kernel_launch(void* const* d_in, const int* in_sizes, int n_in,
                              void* d_out, int out_size, void* d_ws, size_t ws_size,
                              hipStream_t stream)
{
    const float* x        = (const float*)d_in[0];
    const float* ln_w     = (const float*)d_in[1];
    const float* ln_b     = (const float*)d_in[2];
    const float* gate_w   = (const float*)d_in[3];
    const float* gate_b   = (const float*)d_in[4];
    const float* value_w  = (const float*)d_in[5];
    const float* value_b  = (const float*)d_in[6];
    const float* out_w    = (const float*)d_in[7];
    const float* out_b    = (const float*)d_in[8];
    const float* log_dec  = (const float*)d_in[9];
    float* out = (float*)d_out;

    char* ws = (char*)d_ws;
    const size_t MB = 1024 * 1024;
    __hip_bfloat16* normed = (__hip_bfloat16*)(ws);           // 32 MB, reused as S
    __hip_bfloat16* S      = (__hip_bfloat16*)(ws);
    float*          Pk     = (float*)(ws + 32 * MB);          // 1 MB
    __hip_bfloat16* Wg16   = (__hip_bfloat16*)(ws + 33 * MB); // 2 MB
    __hip_bfloat16* Wv16   = (__hip_bfloat16*)(ws + 35 * MB); // 2 MB
    __hip_bfloat16* Wo16   = (__hip_bfloat16*)(ws + 37 * MB); // 2 MB
    __hip_bfloat16* U      = (__hip_bfloat16*)d_out;          // scratch in d_out

    // 0. weight conversion fp32 -> bf16 (single launch)
    convert_w3<<<dim3(3072), dim3(256), 0, stream>>>(
        gate_w, value_w, out_w, Wg16, Wv16, Wo16);

    // 1. LayerNorm: x -> normed (bf16), wave-per-row
    ln_kernel<<<dim3(MM / 4), dim3(256), 0, stream>>>(x, ln_w, ln_b, normed);

    // 2. fused gate+value projections + gating + chunk sums: normed -> U, Pk
    dual_gemm_gate<<<dim3(MM / 128, DD / 128), dim3(256), 0, stream>>>(
        normed, Wg16, Wv16, gate_b, value_b, U, Pk, MM, DD, DD);

    // 3. chunk-offset exclusive scan (in place over Pk), then within-chunk
    //    inclusive scan + decay: U -> S (overwrites normed; it's dead)
    scan_offsets<<<dim3(NC), dim3(256), 0, stream>>>(Pk);
    scan_final<<<dim3(NC, BB), dim3(128), 0, stream>>>(U, Pk, log_dec, S);

    // 4. out = x + S @ out_w^T + out_b   (overwrites U; it's dead)
    gemm_out<<<dim3(MM / 128, DD / 128), dim3(256), 0, stream>>>(
        S, Wo16, out_b, x, out, MM, DD, DD);
}

// Round 4
// 282.406 us; speedup vs baseline: 1.1396x; 1.1396x over previous
//
#include <hip/hip_runtime.h>
#include <hip/hip_bf16.h>

// Problem constants (B=4, T=4096, D=1024). FP32 I/O, bf16 MFMA internally.
#define BB 4
#define TT 4096
#define DD 1024
#define MM (BB * TT)   // 16384 rows
#define LN_EPS 1e-5f

#define NC 64
#define CL 64   // chunk length

typedef __attribute__((ext_vector_type(8))) short bf16x8;   // 8 bf16 = 4 VGPRs
typedef __attribute__((ext_vector_type(4))) float f32x4;

__device__ __forceinline__ float bfbits2f(unsigned short h) {
    return __uint_as_float(((unsigned int)h) << 16);
}
__device__ __forceinline__ unsigned short f2bfbits(float f) {
    __hip_bfloat16 h = __float2bfloat16(f);
    return *reinterpret_cast<unsigned short*>(&h);
}
__device__ __forceinline__ unsigned int pack2(float a, float b) {
    return (unsigned int)f2bfbits(a) | ((unsigned int)f2bfbits(b) << 16);
}

// async global->LDS, 16B per lane (wave-uniform LDS base + lane*16).
__device__ __forceinline__ void async_copy16(void* lds, const void* g) {
    __builtin_amdgcn_global_load_lds(
        (const __attribute__((address_space(1))) void*)g,
        (__attribute__((address_space(3))) void*)lds,
        16, 0, 0);
}

// ---------------------------------------------------------------------------
// MERGED prep: weight fp32->bf16 conversion (blocks 0..3071) + LayerNorm
// (blocks 3072..7167). One launch instead of two; block-uniform branch.
// ---------------------------------------------------------------------------
__global__ __launch_bounds__(256)
void prep_kernel(const float* __restrict__ s0, const float* __restrict__ s1,
                 const float* __restrict__ s2,
                 __hip_bfloat16* __restrict__ d0, __hip_bfloat16* __restrict__ d1,
                 __hip_bfloat16* __restrict__ d2,
                 const float* __restrict__ x,
                 const float* __restrict__ lnw,
                 const float* __restrict__ lnb,
                 __hip_bfloat16* __restrict__ normed)
{
    if (blockIdx.x < 3072) {
        // ---- weight conversion ----
        const int blk = blockIdx.x;
        const int w = blk >> 10;
        const float* src = (w == 0) ? s0 : (w == 1) ? s1 : s2;
        __hip_bfloat16* dst = (w == 0) ? d0 : (w == 1) ? d1 : d2;
        const size_t i = ((size_t)(blk & 1023) * 256 + threadIdx.x) * 4;
        float4 v = *(const float4*)(src + i);
        uint2 o;
        o.x = pack2(v.x, v.y);
        o.y = pack2(v.z, v.w);
        *(uint2*)((unsigned short*)dst + i) = o;
        return;
    }
    // ---- LayerNorm: one wave per row, 4 rows per block ----
    const int wv   = threadIdx.x >> 6;
    const int lane = threadIdx.x & 63;
    const int row  = (blockIdx.x - 3072) * 4 + wv;

    const float* xr = x + (size_t)row * DD + lane * 16;
    float4 v[4];
    #pragma unroll
    for (int i = 0; i < 4; ++i) v[i] = *(const float4*)(xr + i * 4);

    float s = 0.0f, ss = 0.0f;
    #pragma unroll
    for (int i = 0; i < 4; ++i) {
        s  += (v[i].x + v[i].y) + (v[i].z + v[i].w);
        ss += fmaf(v[i].x, v[i].x, fmaf(v[i].y, v[i].y,
              fmaf(v[i].z, v[i].z, v[i].w * v[i].w)));
    }
    #pragma unroll
    for (int o = 32; o > 0; o >>= 1) {
        s  += __shfl_down(s, o);
        ss += __shfl_down(ss, o);
    }
    s  = __shfl(s, 0);
    ss = __shfl(ss, 0);

    const float mu   = s * (1.0f / DD);
    const float var  = ss * (1.0f / DD) - mu * mu;
    const float rstd = rsqrtf(var + LN_EPS);

    unsigned int res[8];
    #pragma unroll
    for (int i = 0; i < 4; ++i) {
        float4 wr = *(const float4*)(lnw + lane * 16 + i * 4);
        float4 br = *(const float4*)(lnb + lane * 16 + i * 4);
        float o0 = (v[i].x - mu) * rstd * wr.x + br.x;
        float o1 = (v[i].y - mu) * rstd * wr.y + br.y;
        float o2 = (v[i].z - mu) * rstd * wr.z + br.z;
        float o3 = (v[i].w - mu) * rstd * wr.w + br.w;
        res[i * 2]     = pack2(o0, o1);
        res[i * 2 + 1] = pack2(o2, o3);
    }
    unsigned short* op = (unsigned short*)normed + (size_t)row * DD + lane * 16;
    *(uint4*)op       = make_uint4(res[0], res[1], res[2], res[3]);
    *(uint4*)(op + 8) = make_uint4(res[4], res[5], res[6], res[7]);
}

// ---------------------------------------------------------------------------
// Fused dual GEMM + gate + CHUNK-SUM epilogue.  (round-0 structure, verified
// 81 us / MfmaUtil 36% / 0 bank conflicts — the proven local optimum; rounds
// 1-3 showed deeper pipelines, phase splits and 32x32 MFMA all regress here.)
// ---------------------------------------------------------------------------
__global__ __launch_bounds__(256, 2)
void dual_gemm_gate(const __hip_bfloat16* __restrict__ A,
                    const __hip_bfloat16* __restrict__ Wg,
                    const __hip_bfloat16* __restrict__ Wv,
                    const float* __restrict__ gb,
                    const float* __restrict__ vb,
                    __hip_bfloat16* __restrict__ U,
                    float* __restrict__ Pk,
                    int M, int N, int K)
{
    constexpr int BK = 64;
    __shared__ short As[128 * BK];   // 16 KB each
    __shared__ short Bg[128 * BK];
    __shared__ short Bv[128 * BK];

    const int tid  = threadIdx.x;
    const int m0   = blockIdx.x * 128;
    const int n0   = blockIdx.y * 128;
    const int wave = tid >> 6;
    const int lane = tid & 63;
    const int wm   = (wave & 1) * 64;
    const int wn   = (wave >> 1) * 64;
    const int lrow = lane & 15;
    const int kgrp = lane >> 4;      // 0..3
    const int swz  = lrow & 7;       // read-side swizzle key

    f32x4 accg[4][4] = {};
    f32x4 accv[4][4] = {};

    // staging: slot = r*256+tid -> row = slot>>3 (0..127), chunk = slot&7.
    // lane fetches global chunk (slot&7) ^ (row&7)  [XOR self-inverse]
    const __hip_bfloat16* gA[4];
    const __hip_bfloat16* gG[4];
    const __hip_bfloat16* gV[4];
    #pragma unroll
    for (int r = 0; r < 4; ++r) {
        const int slot = r * 256 + tid;
        const int srow = slot >> 3;
        const int gcc  = (slot & 7) ^ (srow & 7);
        gA[r] = A  + (size_t)(m0 + srow) * K + gcc * 8;
        gG[r] = Wg + (size_t)(n0 + srow) * K + gcc * 8;
        gV[r] = Wv + (size_t)(n0 + srow) * K + gcc * 8;
    }

    for (int k0 = 0; k0 < K; k0 += BK) {
        #pragma unroll
        for (int r = 0; r < 4; ++r) {
            async_copy16(&As[(r * 256 + tid) * 8], gA[r] + k0);
            async_copy16(&Bg[(r * 256 + tid) * 8], gG[r] + k0);
            async_copy16(&Bv[(r * 256 + tid) * 8], gV[r] + k0);
        }
        __builtin_amdgcn_s_waitcnt(0);
        __syncthreads();

        #pragma unroll
        for (int ks = 0; ks < 2; ++ks) {
            const int co = ((ks * 4 + kgrp) ^ swz) * 8;   // swizzled chunk offset
            bf16x8 af[4], bgf[4], bvf[4];
            #pragma unroll
            for (int i = 0; i < 4; ++i)
                af[i] = *(const bf16x8*)&As[(wm + i * 16 + lrow) * BK + co];
            #pragma unroll
            for (int j = 0; j < 4; ++j) {
                bgf[j] = *(const bf16x8*)&Bg[(wn + j * 16 + lrow) * BK + co];
                bvf[j] = *(const bf16x8*)&Bv[(wn + j * 16 + lrow) * BK + co];
            }
            #pragma unroll
            for (int i = 0; i < 4; ++i)
                #pragma unroll
                for (int j = 0; j < 4; ++j) {
                    accg[i][j] = __builtin_amdgcn_mfma_f32_16x16x32_bf16(
                        bgf[j], af[i], accg[i][j], 0, 0, 0);
                    accv[i][j] = __builtin_amdgcn_mfma_f32_16x16x32_bf16(
                        bvf[j], af[i], accv[i][j], 0, 0, 0);
                }
        }
        __syncthreads();
    }

    // chunk id for this wave's 64 m-rows
    const int chrow = m0 + wm;
    const int cb    = chrow >> 12;            // / TT
    const int cc    = (chrow & (TT - 1)) >> 6; // chunk within batch

    #pragma unroll
    for (int j = 0; j < 4; ++j) {
        const int nb = n0 + wn + j * 16 + kgrp * 4;
        const float4 gb4 = *(const float4*)(gb + nb);
        const float4 vb4 = *(const float4*)(vb + nb);
        float4 ps = make_float4(0.f, 0.f, 0.f, 0.f);
        #pragma unroll
        for (int i = 0; i < 4; ++i) {
            const int m = m0 + wm + i * 16 + lrow;
            const float g0 = accg[i][j][0] + gb4.x, v0 = accv[i][j][0] + vb4.x;
            const float g1 = accg[i][j][1] + gb4.y, v1 = accv[i][j][1] + vb4.y;
            const float g2 = accg[i][j][2] + gb4.z, v2 = accv[i][j][2] + vb4.z;
            const float g3 = accg[i][j][3] + gb4.w, v3 = accv[i][j][3] + vb4.w;
            const float u0 = (2.0f / (1.0f + __expf(-g0)) - 1.0f) * v0;
            const float u1 = (2.0f / (1.0f + __expf(-g1)) - 1.0f) * v1;
            const float u2 = (2.0f / (1.0f + __expf(-g2)) - 1.0f) * v2;
            const float u3 = (2.0f / (1.0f + __expf(-g3)) - 1.0f) * v3;
            ps.x += u0; ps.y += u1; ps.z += u2; ps.w += u3;
            uint2 o;
            o.x = pack2(u0, u1);
            o.y = pack2(u2, u3);
            *(uint2*)((unsigned short*)U + (size_t)m * N + nb) = o;
        }
        // reduce across the 16 lrow-lanes of this kgrp group
        #pragma unroll
        for (int mk = 1; mk <= 8; mk <<= 1) {
            ps.x += __shfl_xor(ps.x, mk);
            ps.y += __shfl_xor(ps.y, mk);
            ps.z += __shfl_xor(ps.z, mk);
            ps.w += __shfl_xor(ps.w, mk);
        }
        if (lrow == 0)
            *(float4*)&Pk[((size_t)cb * NC + cc) * DD + nb] = ps;
    }
}

// ---------------------------------------------------------------------------
// Final GEMM: out[m,n] = X[m,n] + sum_k S[m,k]*Wo[n,k] + ob[n]
// (round-0 structure, verified)
// ---------------------------------------------------------------------------
__global__ __launch_bounds__(256, 2)
void gemm_out(const __hip_bfloat16* __restrict__ A,
              const __hip_bfloat16* __restrict__ W,
              const float* __restrict__ bias,
              const float* __restrict__ X,
              float* __restrict__ C,
              int M, int N, int K)
{
    constexpr int BK = 64;
    __shared__ short As[128 * BK];
    __shared__ short Bs[128 * BK];

    const int tid  = threadIdx.x;
    const int m0   = blockIdx.x * 128;
    const int n0   = blockIdx.y * 128;
    const int wave = tid >> 6;
    const int lane = tid & 63;
    const int wm   = (wave & 1) * 64;
    const int wn   = (wave >> 1) * 64;
    const int lrow = lane & 15;
    const int kgrp = lane >> 4;
    const int swz  = lrow & 7;

    f32x4 acc[4][4] = {};

    const __hip_bfloat16* gA[4];
    const __hip_bfloat16* gB[4];
    #pragma unroll
    for (int r = 0; r < 4; ++r) {
        const int slot = r * 256 + tid;
        const int srow = slot >> 3;
        const int gcc  = (slot & 7) ^ (srow & 7);
        gA[r] = A + (size_t)(m0 + srow) * K + gcc * 8;
        gB[r] = W + (size_t)(n0 + srow) * K + gcc * 8;
    }

    for (int k0 = 0; k0 < K; k0 += BK) {
        #pragma unroll
        for (int r = 0; r < 4; ++r) {
            async_copy16(&As[(r * 256 + tid) * 8], gA[r] + k0);
            async_copy16(&Bs[(r * 256 + tid) * 8], gB[r] + k0);
        }
        __builtin_amdgcn_s_waitcnt(0);
        __syncthreads();

        #pragma unroll
        for (int ks = 0; ks < 2; ++ks) {
            const int co = ((ks * 4 + kgrp) ^ swz) * 8;
            bf16x8 af[4], bfr[4];
            #pragma unroll
            for (int i = 0; i < 4; ++i)
                af[i] = *(const bf16x8*)&As[(wm + i * 16 + lrow) * BK + co];
            #pragma unroll
            for (int j = 0; j < 4; ++j)
                bfr[j] = *(const bf16x8*)&Bs[(wn + j * 16 + lrow) * BK + co];
            #pragma unroll
            for (int i = 0; i < 4; ++i)
                #pragma unroll
                for (int j = 0; j < 4; ++j)
                    acc[i][j] = __builtin_amdgcn_mfma_f32_16x16x32_bf16(
                        bfr[j], af[i], acc[i][j], 0, 0, 0);
        }
        __syncthreads();
    }

    #pragma unroll
    for (int j = 0; j < 4; ++j) {
        const int nb = n0 + wn + j * 16 + kgrp * 4;
        const float4 bv = *(const float4*)(bias + nb);
        #pragma unroll
        for (int i = 0; i < 4; ++i) {
            const int m = m0 + wm + i * 16 + lrow;
            const size_t idx = (size_t)m * N + nb;
            const float4 xv = *(const float4*)(X + idx);
            float4 o;
            o.x = acc[i][j][0] + bv.x + xv.x;
            o.y = acc[i][j][1] + bv.y + xv.y;
            o.z = acc[i][j][2] + bv.z + xv.z;
            o.w = acc[i][j][3] + bv.w + xv.w;
            *(float4*)(C + idx) = o;
        }
    }
}

// ---------------------------------------------------------------------------
// scan_final v2 — 8x wider parallelism + folded chunk-offset prefix.
//   grid (NC, BB) x 1024 threads (16 waves/block, 4096 waves total vs 512).
//   Thread (w, dg): sub-chunk w (8 rows held in REGISTERS, single U read),
//   d-columns d8..d8+7.
//   Phase A: per-column sums of own 8 rows -> LdsC[w][d];
//            partial Pk prefix over chunks cc == w (mod 8), cc < c -> LdsP.
//   Phase B: offset = sum_w' LdsP + sum_{w'<w} LdsC; apply running scan to
//            the registered rows, multiply decay, store S.
//   Pk stays RAW (scan_offsets kernel eliminated); redundant Pk re-reads are
//   L2/L3-resident (Pk = 1 MB).
// ---------------------------------------------------------------------------
__global__ __launch_bounds__(1024)
void scan_final(const __hip_bfloat16* __restrict__ U,
                const float* __restrict__ Pk,
                const float* __restrict__ log_decay,
                __hip_bfloat16* __restrict__ S)
{
    __shared__ float LdsC[8][DD];   // 32 KB
    __shared__ float LdsP[8][DD];   // 32 KB

    const int c  = blockIdx.x, b = blockIdx.y;
    const int w  = threadIdx.x >> 7;     // 0..7 sub-chunk
    const int dg = threadIdx.x & 127;    // d-group
    const int d8 = dg * 8;

    const float ld    = log_decay[0];
    const float alpha = log1pf(__expf(ld));          // softplus
    const float ratio = __expf(-alpha);

    // ---- Phase A: load own 8 rows into registers, per-column sums ----
    const size_t base = ((size_t)b * TT + (size_t)c * CL + w * 8) * DD + d8;
    const unsigned short* up = (const unsigned short*)U + base;

    uint4 raw[8];
    float cs[8] = {0.f, 0.f, 0.f, 0.f, 0.f, 0.f, 0.f, 0.f};
    #pragma unroll
    for (int r = 0; r < 8; ++r) {
        raw[r] = *(const uint4*)(up + (size_t)r * DD);
        const unsigned int wds[4] = {raw[r].x, raw[r].y, raw[r].z, raw[r].w};
        #pragma unroll
        for (int k = 0; k < 4; ++k) {
            cs[2 * k]     += bfbits2f((unsigned short)(wds[k] & 0xFFFF));
            cs[2 * k + 1] += bfbits2f((unsigned short)(wds[k] >> 16));
        }
    }

    // partial exclusive-prefix of Pk: chunks cc = w, w+8, ... < c
    float pp[8] = {0.f, 0.f, 0.f, 0.f, 0.f, 0.f, 0.f, 0.f};
    for (int cc = w; cc < c; cc += 8) {
        const float* pr = &Pk[((size_t)b * NC + cc) * DD + d8];
        const float4 a0 = *(const float4*)pr;
        const float4 a1 = *(const float4*)(pr + 4);
        pp[0] += a0.x; pp[1] += a0.y; pp[2] += a0.z; pp[3] += a0.w;
        pp[4] += a1.x; pp[5] += a1.y; pp[6] += a1.z; pp[7] += a1.w;
    }

    *(float4*)&LdsC[w][d8]     = make_float4(cs[0], cs[1], cs[2], cs[3]);
    *(float4*)&LdsC[w][d8 + 4] = make_float4(cs[4], cs[5], cs[6], cs[7]);
    *(float4*)&LdsP[w][d8]     = make_float4(pp[0], pp[1], pp[2], pp[3]);
    *(float4*)&LdsP[w][d8 + 4] = make_float4(pp[4], pp[5], pp[6], pp[7]);
    __syncthreads();

    // ---- Phase B: combine offsets ----
    float run[8] = {0.f, 0.f, 0.f, 0.f, 0.f, 0.f, 0.f, 0.f};
    #pragma unroll
    for (int w2 = 0; w2 < 8; ++w2) {
        const float4 p0 = *(const float4*)&LdsP[w2][d8];
        const float4 p1 = *(const float4*)&LdsP[w2][d8 + 4];
        run[0] += p0.x; run[1] += p0.y; run[2] += p0.z; run[3] += p0.w;
        run[4] += p1.x; run[5] += p1.y; run[6] += p1.z; run[7] += p1.w;
        if (w2 < w) {
            const float4 c0 = *(const float4*)&LdsC[w2][d8];
            const float4 c1 = *(const float4*)&LdsC[w2][d8 + 4];
            run[0] += c0.x; run[1] += c0.y; run[2] += c0.z; run[3] += c0.w;
            run[4] += c1.x; run[5] += c1.y; run[6] += c1.z; run[7] += c1.w;
        }
    }

    float dec = __expf(-alpha * (float)(c * CL + w * 8));
    unsigned short* sp = (unsigned short*)S + base;
    #pragma unroll
    for (int r = 0; r < 8; ++r) {
        const unsigned int wds[4] = {raw[r].x, raw[r].y, raw[r].z, raw[r].w};
        uint4 o;
        unsigned int* ow = (unsigned int*)&o;
        #pragma unroll
        for (int k = 0; k < 4; ++k) {
            run[2 * k]     += bfbits2f((unsigned short)(wds[k] & 0xFFFF));
            run[2 * k + 1] += bfbits2f((unsigned short)(wds[k] >> 16));
            ow[k] = pack2(run[2 * k] * dec, run[2 * k + 1] * dec);
        }
        *(uint4*)(sp + (size_t)r * DD) = o;
        dec *= ratio;
    }
}

// ---------------------------------------------------------------------------
// Workspace: 39 MB. normed/S 32 MB | Pk 1 MB | Wg/Wv/Wo bf16 2 MB each.
// U (bf16, 32 MB) lives in d_out (fp32 64 MB); dead before gemm_out writes.
// 4 launches total (was 6): prep | dual_gemm_gate | scan_final | gemm_out.
// ---------------------------------------------------------------------------
extern "C" void kernel_launch(void* const* d_in, const int* in_sizes, int n_in,
                              void* d_out, int out_size, void* d_ws, size_t ws_size,
                              hipStream_t stream)
{
    const float* x        = (const float*)d_in[0];
    const float* ln_w     = (const float*)d_in[1];
    const float* ln_b     = (const float*)d_in[2];
    const float* gate_w   = (const float*)d_in[3];
    const float* gate_b   = (const float*)d_in[4];
    const float* value_w  = (const float*)d_in[5];
    const float* value_b  = (const float*)d_in[6];
    const float* out_w    = (const float*)d_in[7];
    const float* out_b    = (const float*)d_in[8];
    const float* log_dec  = (const float*)d_in[9];
    float* out = (float*)d_out;

    char* ws = (char*)d_ws;
    const size_t MB = 1024 * 1024;
    __hip_bfloat16* normed = (__hip_bfloat16*)(ws);           // 32 MB, reused as S
    __hip_bfloat16* S      = (__hip_bfloat16*)(ws);
    float*          Pk     = (float*)(ws + 32 * MB);          // 1 MB (raw chunk sums)
    __hip_bfloat16* Wg16   = (__hip_bfloat16*)(ws + 33 * MB); // 2 MB
    __hip_bfloat16* Wv16   = (__hip_bfloat16*)(ws + 35 * MB); // 2 MB
    __hip_bfloat16* Wo16   = (__hip_bfloat16*)(ws + 37 * MB); // 2 MB
    __hip_bfloat16* U      = (__hip_bfloat16*)d_out;          // scratch in d_out

    // 0+1. weight conversion + LayerNorm in ONE launch
    prep_kernel<<<dim3(3072 + MM / 4), dim3(256), 0, stream>>>(
        gate_w, value_w, out_w, Wg16, Wv16, Wo16, x, ln_w, ln_b, normed);

    // 2. fused gate+value projections + gating + chunk sums: normed -> U, Pk
    dual_gemm_gate<<<dim3(MM / 128, DD / 128), dim3(256), 0, stream>>>(
        normed, Wg16, Wv16, gate_b, value_b, U, Pk, MM, DD, DD);

    // 3. chunk-offset prefix (folded) + within-chunk scan + decay: U -> S
    scan_final<<<dim3(NC, BB), dim3(1024), 0, stream>>>(U, Pk, log_dec, S);

    // 4. out = x + S @ out_w^T + out_b   (overwrites U; it's dead)
    gemm_out<<<dim3(MM / 128, DD / 128), dim3(256), 0, stream>>>(
        S, Wo16, out_b, x, out, MM, DD, DD);
}

// Round 5
// 266.648 us; speedup vs baseline: 1.2070x; 1.0591x over previous
//
#include <hip/hip_runtime.h>
#include <hip/hip_bf16.h>

// Problem constants (B=4, T=4096, D=1024). FP32 I/O, bf16 MFMA internally.
#define BB 4
#define TT 4096
#define DD 1024
#define MM (BB * TT)   // 16384 rows
#define LN_EPS 1e-5f

#define NC 64
#define CL 64   // chunk length

typedef __attribute__((ext_vector_type(8))) short bf16x8;   // 8 bf16 = 4 VGPRs
typedef __attribute__((ext_vector_type(4))) float f32x4;

__device__ __forceinline__ float bfbits2f(unsigned short h) {
    return __uint_as_float(((unsigned int)h) << 16);
}
__device__ __forceinline__ unsigned short f2bfbits(float f) {
    __hip_bfloat16 h = __float2bfloat16(f);
    return *reinterpret_cast<unsigned short*>(&h);
}
__device__ __forceinline__ unsigned int pack2(float a, float b) {
    return (unsigned int)f2bfbits(a) | ((unsigned int)f2bfbits(b) << 16);
}

// async global->LDS, 16B per lane (wave-uniform LDS base + lane*16).
__device__ __forceinline__ void async_copy16(void* lds, const void* g) {
    __builtin_amdgcn_global_load_lds(
        (const __attribute__((address_space(1))) void*)g,
        (__attribute__((address_space(3))) void*)lds,
        16, 0, 0);
}

#define RAW_BAR() asm volatile("s_barrier" ::: "memory")

// ---------------------------------------------------------------------------
// MERGED prep: weight fp32->bf16 conversion (blocks 0..3071) + LayerNorm
// (blocks 3072..7167).
// Wg/Wv are ROW-INTERLEAVED into one [2048][1024] matrix Wgv:
//   row 2d = Wg row d, row 2d+1 = Wv row d.
// The dual projection then becomes ONE GEMM with N'=2048 whose output
// columns alternate g_d, v_d — pairs land inside one acc register quad.
// ---------------------------------------------------------------------------
__global__ __launch_bounds__(256)
void prep_kernel(const float* __restrict__ s0, const float* __restrict__ s1,
                 const float* __restrict__ s2,
                 __hip_bfloat16* __restrict__ dGV,  // [2048][1024] interleaved
                 __hip_bfloat16* __restrict__ dO,   // [1024][1024]
                 const float* __restrict__ x,
                 const float* __restrict__ lnw,
                 const float* __restrict__ lnb,
                 __hip_bfloat16* __restrict__ normed)
{
    if (blockIdx.x < 3072) {
        const int blk = blockIdx.x;
        const int w = blk >> 10;
        const float* src = (w == 0) ? s0 : (w == 1) ? s1 : s2;
        const size_t i = ((size_t)(blk & 1023) * 256 + threadIdx.x) * 4;
        float4 v = *(const float4*)(src + i);
        uint2 o;
        o.x = pack2(v.x, v.y);
        o.y = pack2(v.z, v.w);
        size_t di;
        if (w == 2) di = i;                                   // Wo: plain
        else        di = ((((i >> 10) << 1) | (size_t)w) << 10) | (i & 1023);
        __hip_bfloat16* dst = (w == 2) ? dO : dGV;
        *(uint2*)((unsigned short*)dst + di) = o;
        return;
    }
    // ---- LayerNorm: one wave per row, 4 rows per block ----
    const int wv   = threadIdx.x >> 6;
    const int lane = threadIdx.x & 63;
    const int row  = (blockIdx.x - 3072) * 4 + wv;

    const float* xr = x + (size_t)row * DD + lane * 16;
    float4 v[4];
    #pragma unroll
    for (int i = 0; i < 4; ++i) v[i] = *(const float4*)(xr + i * 4);

    float s = 0.0f, ss = 0.0f;
    #pragma unroll
    for (int i = 0; i < 4; ++i) {
        s  += (v[i].x + v[i].y) + (v[i].z + v[i].w);
        ss += fmaf(v[i].x, v[i].x, fmaf(v[i].y, v[i].y,
              fmaf(v[i].z, v[i].z, v[i].w * v[i].w)));
    }
    #pragma unroll
    for (int o = 32; o > 0; o >>= 1) {
        s  += __shfl_down(s, o);
        ss += __shfl_down(ss, o);
    }
    s  = __shfl(s, 0);
    ss = __shfl(ss, 0);

    const float mu   = s * (1.0f / DD);
    const float var  = ss * (1.0f / DD) - mu * mu;
    const float rstd = rsqrtf(var + LN_EPS);

    unsigned int res[8];
    #pragma unroll
    for (int i = 0; i < 4; ++i) {
        float4 wr = *(const float4*)(lnw + lane * 16 + i * 4);
        float4 br = *(const float4*)(lnb + lane * 16 + i * 4);
        float o0 = (v[i].x - mu) * rstd * wr.x + br.x;
        float o1 = (v[i].y - mu) * rstd * wr.y + br.y;
        float o2 = (v[i].z - mu) * rstd * wr.z + br.z;
        float o3 = (v[i].w - mu) * rstd * wr.w + br.w;
        res[i * 2]     = pack2(o0, o1);
        res[i * 2 + 1] = pack2(o2, o3);
    }
    unsigned short* op = (unsigned short*)normed + (size_t)row * DD + lane * 16;
    *(uint4*)op       = make_uint4(res[0], res[1], res[2], res[3]);
    *(uint4*)(op + 8) = make_uint4(res[4], res[5], res[6], res[7]);
}

// ---------------------------------------------------------------------------
// 256x256 8-phase K-loop core (m201 geometry, plain HIP).
//   8 waves (2M x 4N), per-wave output 128x64; BK=64; LDS 128 KiB
//   (A,B double-buffered: even K-tiles in buf0, odd in buf1).
//   Per iteration = 2 K-tiles = 8 phases; each phase:
//     {ds_read frags | issue 4 staging loads} -> s_barrier ->
//     setprio(1) -> 16 MFMA (one C-quadrant x K=64) -> setprio(0) -> s_barrier
//   Counted vmcnt: ph3 protects buf1 (4 younger loads = ph3's A-stage),
//   ph7 protects buf0 (4 younger = ph7's A-stage). Never 0 until last tile.
//   Staging order: prologue A0,B0,A1; then per iter:
//     ph0: B(2i+1)->Bb1   ph3: A(2i+2)->Ab0   ph4: B(2i+2)->Bb0
//     ph7: A(2i+3)->Ab1
//   Overwrite hazards: each staged region's last ds_read is >=1 barrier
//   before the stage issue (buf0-A read ph0/ph2, staged ph3; buf0-B read
//   ph0/ph1, staged ph4; buf1-A read ph4/ph6, staged ph7; buf1-B read
//   ph4/ph5, staged next-iter ph0).
// ---------------------------------------------------------------------------
__device__ __forceinline__ void kloop256(
    const __hip_bfloat16* __restrict__ Aglb,
    const __hip_bfloat16* __restrict__ Bglb,
    short* Ab0, short* Ab1, short* Bb0, short* Bb1,
    int m0, int n0, int tid, f32x4 acc[8][4])
{
    constexpr int BK = 64;
    constexpr int K  = DD;
    const int lane = tid & 63;
    const int wave = tid >> 6;
    const int wrow = (wave & 1) * 128;
    const int wcol = (wave >> 1) * 64;
    const int lrow = lane & 15;
    const int kgrp = lane >> 4;
    const int swz  = lrow & 7;

    const __hip_bfloat16* gA[4];
    const __hip_bfloat16* gB[4];
    #pragma unroll
    for (int r = 0; r < 4; ++r) {
        const int slot = r * 512 + tid;
        const int srow = slot >> 3;              // 0..255
        const int gcc  = (slot & 7) ^ (srow & 7);
        gA[r] = Aglb + (size_t)(m0 + srow) * K + gcc * 8;
        gB[r] = Bglb + (size_t)(n0 + srow) * K + gcc * 8;
    }
    auto stA = [&](short* buf, int kofs) {
        #pragma unroll
        for (int r = 0; r < 4; ++r)
            async_copy16(&buf[(r * 512 + tid) * 8], gA[r] + kofs);
    };
    auto stB = [&](short* buf, int kofs) {
        #pragma unroll
        for (int r = 0; r < 4; ++r)
            async_copy16(&buf[(r * 512 + tid) * 8], gB[r] + kofs);
    };

    // prologue: A0, B0, A1 in flight (12 loads); wait A0+B0 (4 newest = A1)
    stA(Ab0, 0);
    stB(Bb0, 0);
    stA(Ab1, BK);
    asm volatile("s_waitcnt vmcnt(4)" ::: "memory");
    __builtin_amdgcn_s_barrier();

    bf16x8 a[4][2], b01[2][2], b23[2][2];

    for (int it = 0; it < 8; ++it) {
        const bool sT2 = (2 * it + 2) < 16;   // tile 2i+2 exists
        const bool sT3 = (2 * it + 3) < 16;   // tile 2i+3 exists
        const int kB1 = (2 * it + 1) * BK;
        const int kT2 = (2 * it + 2) * BK;
        const int kT3 = (2 * it + 3) * BK;

        // ================= buf0: tile 2it =================
        // ---- ph0: quadrant (m0-3, n0-1), 12 ds_reads ----
        #pragma unroll
        for (int f = 0; f < 4; ++f)
            #pragma unroll
            for (int ks = 0; ks < 2; ++ks)
                a[f][ks] = *(const bf16x8*)&Ab0[(wrow + f * 16 + lrow) * BK +
                                                (((ks * 4 + kgrp) ^ swz) * 8)];
        #pragma unroll
        for (int j = 0; j < 2; ++j)
            #pragma unroll
            for (int ks = 0; ks < 2; ++ks)
                b01[j][ks] = *(const bf16x8*)&Bb0[(wcol + j * 16 + lrow) * BK +
                                                  (((ks * 4 + kgrp) ^ swz) * 8)];
        stB(Bb1, kB1);
        RAW_BAR();
        __builtin_amdgcn_s_setprio(1);
        #pragma unroll
        for (int ks = 0; ks < 2; ++ks)
            #pragma unroll
            for (int f = 0; f < 4; ++f)
                #pragma unroll
                for (int j = 0; j < 2; ++j)
                    acc[f][j] = __builtin_amdgcn_mfma_f32_16x16x32_bf16(
                        b01[j][ks], a[f][ks], acc[f][j], 0, 0, 0);
        __builtin_amdgcn_s_setprio(0);
        RAW_BAR();

        // ---- ph1: (m0-3, n2-3), 4 ds_reads ----
        #pragma unroll
        for (int j = 0; j < 2; ++j)
            #pragma unroll
            for (int ks = 0; ks < 2; ++ks)
                b23[j][ks] = *(const bf16x8*)&Bb0[(wcol + 32 + j * 16 + lrow) * BK +
                                                  (((ks * 4 + kgrp) ^ swz) * 8)];
        RAW_BAR();
        __builtin_amdgcn_s_setprio(1);
        #pragma unroll
        for (int ks = 0; ks < 2; ++ks)
            #pragma unroll
            for (int f = 0; f < 4; ++f)
                #pragma unroll
                for (int j = 0; j < 2; ++j)
                    acc[f][2 + j] = __builtin_amdgcn_mfma_f32_16x16x32_bf16(
                        b23[j][ks], a[f][ks], acc[f][2 + j], 0, 0, 0);
        __builtin_amdgcn_s_setprio(0);
        RAW_BAR();

        // ---- ph2: (m4-7, n0-1), 8 ds_reads ----
        #pragma unroll
        for (int f = 0; f < 4; ++f)
            #pragma unroll
            for (int ks = 0; ks < 2; ++ks)
                a[f][ks] = *(const bf16x8*)&Ab0[(wrow + 64 + f * 16 + lrow) * BK +
                                                (((ks * 4 + kgrp) ^ swz) * 8)];
        RAW_BAR();
        __builtin_amdgcn_s_setprio(1);
        #pragma unroll
        for (int ks = 0; ks < 2; ++ks)
            #pragma unroll
            for (int f = 0; f < 4; ++f)
                #pragma unroll
                for (int j = 0; j < 2; ++j)
                    acc[4 + f][j] = __builtin_amdgcn_mfma_f32_16x16x32_bf16(
                        b01[j][ks], a[f][ks], acc[4 + f][j], 0, 0, 0);
        __builtin_amdgcn_s_setprio(0);
        RAW_BAR();

        // ---- ph3: (m4-7, n2-3); stage A(2i+2); counted wait for buf1 ----
        if (sT2) stA(Ab0, kT2);
        if (sT2) asm volatile("s_waitcnt vmcnt(4)" ::: "memory");
        else     asm volatile("s_waitcnt vmcnt(0)" ::: "memory");
        RAW_BAR();
        __builtin_amdgcn_s_setprio(1);
        #pragma unroll
        for (int ks = 0; ks < 2; ++ks)
            #pragma unroll
            for (int f = 0; f < 4; ++f)
                #pragma unroll
                for (int j = 0; j < 2; ++j)
                    acc[4 + f][2 + j] = __builtin_amdgcn_mfma_f32_16x16x32_bf16(
                        b23[j][ks], a[f][ks], acc[4 + f][2 + j], 0, 0, 0);
        __builtin_amdgcn_s_setprio(0);
        RAW_BAR();

        // ================= buf1: tile 2it+1 =================
        // ---- ph4: (m0-3, n0-1) ----
        #pragma unroll
        for (int f = 0; f < 4; ++f)
            #pragma unroll
            for (int ks = 0; ks < 2; ++ks)
                a[f][ks] = *(const bf16x8*)&Ab1[(wrow + f * 16 + lrow) * BK +
                                                (((ks * 4 + kgrp) ^ swz) * 8)];
        #pragma unroll
        for (int j = 0; j < 2; ++j)
            #pragma unroll
            for (int ks = 0; ks < 2; ++ks)
                b01[j][ks] = *(const bf16x8*)&Bb1[(wcol + j * 16 + lrow) * BK +
                                                  (((ks * 4 + kgrp) ^ swz) * 8)];
        if (sT2) stB(Bb0, kT2);
        RAW_BAR();
        __builtin_amdgcn_s_setprio(1);
        #pragma unroll
        for (int ks = 0; ks < 2; ++ks)
            #pragma unroll
            for (int f = 0; f < 4; ++f)
                #pragma unroll
                for (int j = 0; j < 2; ++j)
                    acc[f][j] = __builtin_amdgcn_mfma_f32_16x16x32_bf16(
                        b01[j][ks], a[f][ks], acc[f][j], 0, 0, 0);
        __builtin_amdgcn_s_setprio(0);
        RAW_BAR();

        // ---- ph5: (m0-3, n2-3) ----
        #pragma unroll
        for (int j = 0; j < 2; ++j)
            #pragma unroll
            for (int ks = 0; ks < 2; ++ks)
                b23[j][ks] = *(const bf16x8*)&Bb1[(wcol + 32 + j * 16 + lrow) * BK +
                                                  (((ks * 4 + kgrp) ^ swz) * 8)];
        RAW_BAR();
        __builtin_amdgcn_s_setprio(1);
        #pragma unroll
        for (int ks = 0; ks < 2; ++ks)
            #pragma unroll
            for (int f = 0; f < 4; ++f)
                #pragma unroll
                for (int j = 0; j < 2; ++j)
                    acc[f][2 + j] = __builtin_amdgcn_mfma_f32_16x16x32_bf16(
                        b23[j][ks], a[f][ks], acc[f][2 + j], 0, 0, 0);
        __builtin_amdgcn_s_setprio(0);
        RAW_BAR();

        // ---- ph6: (m4-7, n0-1) ----
        #pragma unroll
        for (int f = 0; f < 4; ++f)
            #pragma unroll
            for (int ks = 0; ks < 2; ++ks)
                a[f][ks] = *(const bf16x8*)&Ab1[(wrow + 64 + f * 16 + lrow) * BK +
                                                (((ks * 4 + kgrp) ^ swz) * 8)];
        RAW_BAR();
        __builtin_amdgcn_s_setprio(1);
        #pragma unroll
        for (int ks = 0; ks < 2; ++ks)
            #pragma unroll
            for (int f = 0; f < 4; ++f)
                #pragma unroll
                for (int j = 0; j < 2; ++j)
                    acc[4 + f][j] = __builtin_amdgcn_mfma_f32_16x16x32_bf16(
                        b01[j][ks], a[f][ks], acc[4 + f][j], 0, 0, 0);
        __builtin_amdgcn_s_setprio(0);
        RAW_BAR();

        // ---- ph7: (m4-7, n2-3); stage A(2i+3); counted wait for buf0 ----
        if (sT3) stA(Ab1, kT3);
        if (it < 7) {
            if (sT3) asm volatile("s_waitcnt vmcnt(4)" ::: "memory");
            else     asm volatile("s_waitcnt vmcnt(0)" ::: "memory");
        }
        RAW_BAR();
        __builtin_amdgcn_s_setprio(1);
        #pragma unroll
        for (int ks = 0; ks < 2; ++ks)
            #pragma unroll
            for (int f = 0; f < 4; ++f)
                #pragma unroll
                for (int j = 0; j < 2; ++j)
                    acc[4 + f][2 + j] = __builtin_amdgcn_mfma_f32_16x16x32_bf16(
                        b23[j][ks], a[f][ks], acc[4 + f][2 + j], 0, 0, 0);
        __builtin_amdgcn_s_setprio(0);
        RAW_BAR();
    }
}

// ---------------------------------------------------------------------------
// Dual projection as ONE 256x256 GEMM over interleaved Wgv (N'=2048),
// + gate epilogue + chunk sums. acc quad = (g_d, v_d, g_{d+1}, v_{d+1}).
// ---------------------------------------------------------------------------
__global__ __launch_bounds__(512, 2)
void dual_gemm_gate(const __hip_bfloat16* __restrict__ A,
                    const __hip_bfloat16* __restrict__ Wgv,
                    const float* __restrict__ gb,
                    const float* __restrict__ vb,
                    __hip_bfloat16* __restrict__ U,
                    float* __restrict__ Pk)
{
    __shared__ short Ab[2][256 * 64];
    __shared__ short Bb[2][256 * 64];

    const int tid = threadIdx.x;
    const int m0  = blockIdx.x * 256;
    const int n0  = blockIdx.y * 256;   // n' in [0,2048)

    f32x4 acc[8][4] = {};
    kloop256(A, Wgv, Ab[0], Ab[1], Bb[0], Bb[1], m0, n0, tid, acc);

    const int lane = tid & 63;
    const int wave = tid >> 6;
    const int wrow = (wave & 1) * 128;
    const int wcol = (wave >> 1) * 64;
    const int lrow = lane & 15;
    const int kgrp = lane >> 4;

    const int dbase = ((n0 + wcol) >> 1) + kgrp * 2;
    float2 gb2[4], vb2[4];
    #pragma unroll
    for (int j = 0; j < 4; ++j) {
        gb2[j] = *(const float2*)(gb + dbase + j * 8);
        vb2[j] = *(const float2*)(vb + dbase + j * 8);
    }

    float psx0[4] = {}, psy0[4] = {}, psx1[4] = {}, psy1[4] = {};
    #pragma unroll
    for (int f = 0; f < 8; ++f) {
        const int m = m0 + wrow + f * 16 + lrow;
        unsigned short* urow = (unsigned short*)U + (size_t)m * DD;
        #pragma unroll
        for (int j = 0; j < 4; ++j) {
            const int db = dbase + j * 8;
            const float g0 = acc[f][j][0] + gb2[j].x;
            const float v0 = acc[f][j][1] + vb2[j].x;
            const float g1 = acc[f][j][2] + gb2[j].y;
            const float v1 = acc[f][j][3] + vb2[j].y;
            const float u0 = (2.0f / (1.0f + __expf(-g0)) - 1.0f) * v0;
            const float u1 = (2.0f / (1.0f + __expf(-g1)) - 1.0f) * v1;
            *(unsigned int*)(urow + db) = pack2(u0, u1);
            if (f < 4) { psx0[j] += u0; psy0[j] += u1; }
            else       { psx1[j] += u0; psy1[j] += u1; }
        }
    }
    // reduce over the 16 lrow lanes of this kgrp group
    #pragma unroll
    for (int j = 0; j < 4; ++j) {
        #pragma unroll
        for (int mk = 1; mk <= 8; mk <<= 1) {
            psx0[j] += __shfl_xor(psx0[j], mk);
            psy0[j] += __shfl_xor(psy0[j], mk);
            psx1[j] += __shfl_xor(psx1[j], mk);
            psy1[j] += __shfl_xor(psy1[j], mk);
        }
    }
    if (lrow == 0) {
        const int grow = m0 + wrow;               // multiple of 128
        const int cb   = grow >> 12;              // / TT
        const int cc   = (grow & (TT - 1)) >> 6;  // chunk within batch
        #pragma unroll
        for (int j = 0; j < 4; ++j) {
            const int db = dbase + j * 8;
            *(float2*)&Pk[((size_t)cb * NC + cc) * DD + db] =
                make_float2(psx0[j], psy0[j]);
            *(float2*)&Pk[((size_t)cb * NC + cc + 1) * DD + db] =
                make_float2(psx1[j], psy1[j]);
        }
    }
}

// ---------------------------------------------------------------------------
// Final GEMM: out[m,n] = X[m,n] + sum_k S[m,k]*Wo[n,k] + ob[n]
// Same 256x256 8-phase core. Grid (64,4) = 256 blocks = 1/CU.
// ---------------------------------------------------------------------------
__global__ __launch_bounds__(512, 2)
void gemm_out(const __hip_bfloat16* __restrict__ S,
              const __hip_bfloat16* __restrict__ Wo,
              const float* __restrict__ bias,
              const float* __restrict__ X,
              float* __restrict__ C)
{
    __shared__ short Ab[2][256 * 64];
    __shared__ short Bb[2][256 * 64];

    const int tid = threadIdx.x;
    const int m0  = blockIdx.x * 256;
    const int n0  = blockIdx.y * 256;

    f32x4 acc[8][4] = {};
    kloop256(S, Wo, Ab[0], Ab[1], Bb[0], Bb[1], m0, n0, tid, acc);

    const int lane = tid & 63;
    const int wave = tid >> 6;
    const int wrow = (wave & 1) * 128;
    const int wcol = (wave >> 1) * 64;
    const int lrow = lane & 15;
    const int kgrp = lane >> 4;

    float4 bv[4];
    #pragma unroll
    for (int j = 0; j < 4; ++j)
        bv[j] = *(const float4*)(bias + n0 + wcol + j * 16 + kgrp * 4);

    #pragma unroll
    for (int f = 0; f < 8; ++f) {
        const int m = m0 + wrow + f * 16 + lrow;
        #pragma unroll
        for (int j = 0; j < 4; ++j) {
            const int nb = n0 + wcol + j * 16 + kgrp * 4;
            const size_t idx = (size_t)m * DD + nb;
            const float4 xv = *(const float4*)(X + idx);
            float4 o;
            o.x = acc[f][j][0] + bv[j].x + xv.x;
            o.y = acc[f][j][1] + bv[j].y + xv.y;
            o.z = acc[f][j][2] + bv[j].z + xv.z;
            o.w = acc[f][j][3] + bv[j].w + xv.w;
            *(float4*)(C + idx) = o;
        }
    }
}

// ---------------------------------------------------------------------------
// scan_final — 8x-wide within-chunk scan + folded chunk-offset prefix.
// (round-4 version, verified)
// ---------------------------------------------------------------------------
__global__ __launch_bounds__(1024)
void scan_final(const __hip_bfloat16* __restrict__ U,
                const float* __restrict__ Pk,
                const float* __restrict__ log_decay,
                __hip_bfloat16* __restrict__ S)
{
    __shared__ float LdsC[8][DD];   // 32 KB
    __shared__ float LdsP[8][DD];   // 32 KB

    const int c  = blockIdx.x, b = blockIdx.y;
    const int w  = threadIdx.x >> 7;     // 0..7 sub-chunk
    const int dg = threadIdx.x & 127;    // d-group
    const int d8 = dg * 8;

    const float ld    = log_decay[0];
    const float alpha = log1pf(__expf(ld));          // softplus
    const float ratio = __expf(-alpha);

    const size_t base = ((size_t)b * TT + (size_t)c * CL + w * 8) * DD + d8;
    const unsigned short* up = (const unsigned short*)U + base;

    uint4 raw[8];
    float cs[8] = {0.f, 0.f, 0.f, 0.f, 0.f, 0.f, 0.f, 0.f};
    #pragma unroll
    for (int r = 0; r < 8; ++r) {
        raw[r] = *(const uint4*)(up + (size_t)r * DD);
        const unsigned int wds[4] = {raw[r].x, raw[r].y, raw[r].z, raw[r].w};
        #pragma unroll
        for (int k = 0; k < 4; ++k) {
            cs[2 * k]     += bfbits2f((unsigned short)(wds[k] & 0xFFFF));
            cs[2 * k + 1] += bfbits2f((unsigned short)(wds[k] >> 16));
        }
    }

    float pp[8] = {0.f, 0.f, 0.f, 0.f, 0.f, 0.f, 0.f, 0.f};
    for (int cc = w; cc < c; cc += 8) {
        const float* pr = &Pk[((size_t)b * NC + cc) * DD + d8];
        const float4 a0 = *(const float4*)pr;
        const float4 a1 = *(const float4*)(pr + 4);
        pp[0] += a0.x; pp[1] += a0.y; pp[2] += a0.z; pp[3] += a0.w;
        pp[4] += a1.x; pp[5] += a1.y; pp[6] += a1.z; pp[7] += a1.w;
    }

    *(float4*)&LdsC[w][d8]     = make_float4(cs[0], cs[1], cs[2], cs[3]);
    *(float4*)&LdsC[w][d8 + 4] = make_float4(cs[4], cs[5], cs[6], cs[7]);
    *(float4*)&LdsP[w][d8]     = make_float4(pp[0], pp[1], pp[2], pp[3]);
    *(float4*)&LdsP[w][d8 + 4] = make_float4(pp[4], pp[5], pp[6], pp[7]);
    __syncthreads();

    float run[8] = {0.f, 0.f, 0.f, 0.f, 0.f, 0.f, 0.f, 0.f};
    #pragma unroll
    for (int w2 = 0; w2 < 8; ++w2) {
        const float4 p0 = *(const float4*)&LdsP[w2][d8];
        const float4 p1 = *(const float4*)&LdsP[w2][d8 + 4];
        run[0] += p0.x; run[1] += p0.y; run[2] += p0.z; run[3] += p0.w;
        run[4] += p1.x; run[5] += p1.y; run[6] += p1.z; run[7] += p1.w;
        if (w2 < w) {
            const float4 c0 = *(const float4*)&LdsC[w2][d8];
            const float4 c1 = *(const float4*)&LdsC[w2][d8 + 4];
            run[0] += c0.x; run[1] += c0.y; run[2] += c0.z; run[3] += c0.w;
            run[4] += c1.x; run[5] += c1.y; run[6] += c1.z; run[7] += c1.w;
        }
    }

    float dec = __expf(-alpha * (float)(c * CL + w * 8));
    unsigned short* sp = (unsigned short*)S + base;
    #pragma unroll
    for (int r = 0; r < 8; ++r) {
        const unsigned int wds[4] = {raw[r].x, raw[r].y, raw[r].z, raw[r].w};
        uint4 o;
        unsigned int* ow = (unsigned int*)&o;
        #pragma unroll
        for (int k = 0; k < 4; ++k) {
            run[2 * k]     += bfbits2f((unsigned short)(wds[k] & 0xFFFF));
            run[2 * k + 1] += bfbits2f((unsigned short)(wds[k] >> 16));
            ow[k] = pack2(run[2 * k] * dec, run[2 * k + 1] * dec);
        }
        *(uint4*)(sp + (size_t)r * DD) = o;
        dec *= ratio;
    }
}

// ---------------------------------------------------------------------------
// Workspace: 39 MB. normed/S 32 MB | Pk 1 MB | Wgv bf16 4 MB | Wo bf16 2 MB.
// U (bf16, 32 MB) lives in d_out (fp32 64 MB); dead before gemm_out writes.
// ---------------------------------------------------------------------------
extern "C" void kernel_launch(void* const* d_in, const int* in_sizes, int n_in,
                              void* d_out, int out_size, void* d_ws, size_t ws_size,
                              hipStream_t stream)
{
    const float* x        = (const float*)d_in[0];
    const float* ln_w     = (const float*)d_in[1];
    const float* ln_b     = (const float*)d_in[2];
    const float* gate_w   = (const float*)d_in[3];
    const float* gate_b   = (const float*)d_in[4];
    const float* value_w  = (const float*)d_in[5];
    const float* value_b  = (const float*)d_in[6];
    const float* out_w    = (const float*)d_in[7];
    const float* out_b    = (const float*)d_in[8];
    const float* log_dec  = (const float*)d_in[9];
    float* out = (float*)d_out;

    char* ws = (char*)d_ws;
    const size_t MB = 1024 * 1024;
    __hip_bfloat16* normed = (__hip_bfloat16*)(ws);           // 32 MB, reused as S
    __hip_bfloat16* S      = (__hip_bfloat16*)(ws);
    float*          Pk     = (float*)(ws + 32 * MB);          // 1 MB (raw chunk sums)
    __hip_bfloat16* Wgv16  = (__hip_bfloat16*)(ws + 33 * MB); // 4 MB interleaved
    __hip_bfloat16* Wo16   = (__hip_bfloat16*)(ws + 37 * MB); // 2 MB
    __hip_bfloat16* U      = (__hip_bfloat16*)d_out;          // scratch in d_out

    // 0+1. weight conversion (interleaved Wgv) + LayerNorm in ONE launch
    prep_kernel<<<dim3(3072 + MM / 4), dim3(256), 0, stream>>>(
        gate_w, value_w, out_w, Wgv16, Wo16, x, ln_w, ln_b, normed);

    // 2. dual projection as single 256^2 8-phase GEMM (N'=2048) + gate + Pk
    dual_gemm_gate<<<dim3(MM / 256, 2048 / 256), dim3(512), 0, stream>>>(
        normed, Wgv16, gate_b, value_b, U, Pk);

    // 3. chunk-offset prefix (folded) + within-chunk scan + decay: U -> S
    scan_final<<<dim3(NC, BB), dim3(1024), 0, stream>>>(U, Pk, log_dec, S);

    // 4. out = x + S @ out_w^T + out_b  (256^2 8-phase; overwrites U, it's dead)
    gemm_out<<<dim3(MM / 256, DD / 256), dim3(512), 0, stream>>>(
        S, Wo16, out_b, x, out);
}